// Round 1
// baseline (1074.739 us; speedup 1.0000x reference)
//
#include <hip/hip_runtime.h>

#define BB 64
#define LL 2048
#define HH 512
#define DDIM 1024
#define VV 50257
#define KK 1536

typedef float f32x4 __attribute__((ext_vector_type(4)));
typedef __bf16 bf16x8 __attribute__((ext_vector_type(8)));

// ---------------- K1: partial sums of encoder_out over L (context = mean) ----
__global__ void k_ctx_partial(const float* __restrict__ enc, float* __restrict__ part) {
    int b = blockIdx.x, c = blockIdx.y, t = threadIdx.x;
    const float4* p = reinterpret_cast<const float4*>(enc + ((size_t)b*LL + (size_t)c*128)*DDIM) + t;
    float sx=0.f, sy=0.f, sz=0.f, sw=0.f;
    #pragma unroll 4
    for (int l = 0; l < 128; ++l) {
        float4 v = p[(size_t)l*(DDIM/4)];
        sx += v.x; sy += v.y; sz += v.z; sw += v.w;
    }
    float4 o; o.x=sx; o.y=sy; o.z=sz; o.w=sw;
    reinterpret_cast<float4*>(part + ((size_t)b*16 + c)*DDIM)[t] = o;
}

// ---------------- K2: finalize context, emb gather, build actT/h0T, y-ctx, attnw
__global__ void k_prep(const float* __restrict__ part, const int* __restrict__ x,
                       const float* __restrict__ emb, const float* __restrict__ h,
                       float* __restrict__ actT, __bf16* __restrict__ y,
                       float* __restrict__ attnw) {
    int b = blockIdx.x, t = threadIdx.x;
    float sx=0.f, sy=0.f, sz=0.f, sw=0.f;
    #pragma unroll
    for (int c = 0; c < 16; ++c) {
        float4 v = reinterpret_cast<const float4*>(part + ((size_t)b*16 + c)*DDIM)[t];
        sx += v.x; sy += v.y; sz += v.z; sw += v.w;
    }
    const float inv = 1.0f/2048.0f;
    sx *= inv; sy *= inv; sz *= inv; sw *= inv;
    int d = 4*t;
    // context rows of actT (xt = [xe(512) | ctx(1024)])
    actT[(size_t)(512+d+0)*BB + b] = sx;
    actT[(size_t)(512+d+1)*BB + b] = sy;
    actT[(size_t)(512+d+2)*BB + b] = sz;
    actT[(size_t)(512+d+3)*BB + b] = sw;
    // context half of y (logits A-operand, bf16, row-major [64][1536])
    __bf16* yp = y + (size_t)b*KK + 512 + d;
    yp[0]=(__bf16)sx; yp[1]=(__bf16)sy; yp[2]=(__bf16)sz; yp[3]=(__bf16)sw;
    if (t < 128) {
        int xb = x[b];
        float4 e4 = reinterpret_cast<const float4*>(emb + (size_t)xb*512)[t];
        int dd = 4*t;
        actT[(size_t)(dd+0)*BB+b]=e4.x; actT[(size_t)(dd+1)*BB+b]=e4.y;
        actT[(size_t)(dd+2)*BB+b]=e4.z; actT[(size_t)(dd+3)*BB+b]=e4.w;
    } else {
        int tt = t - 128;
        float4 h4 = reinterpret_cast<const float4*>(h + (size_t)b*HH)[tt];
        int dd = 4*tt;
        actT[(size_t)(1536+dd+0)*BB+b]=h4.x; actT[(size_t)(1536+dd+1)*BB+b]=h4.y;
        actT[(size_t)(1536+dd+2)*BB+b]=h4.z; actT[(size_t)(1536+dd+3)*BB+b]=h4.w;
    }
    // attn_weights output: exactly uniform 1/2048
    #pragma unroll
    for (int i = 0; i < 8; ++i) attnw[(size_t)b*LL + t + 256*i] = inv;
}

// ---------------- K3: split-K fp32 partial GEMM  P[kc][g][b] = sum_k AT[k][b]*W[g][k]
__global__ void k_small_gemm(const float* __restrict__ AT, const float* __restrict__ W,
                             float* __restrict__ P, int Ktot, int kc_len, int Nn) {
    int lane = threadIdx.x;            // blockDim = 64, lane = b
    int g0 = blockIdx.x * 8;
    int kc = blockIdx.y;
    int k0 = kc * kc_len;
    float acc[8];
    #pragma unroll
    for (int j = 0; j < 8; ++j) acc[j] = 0.f;
    #pragma unroll 4
    for (int k = k0; k < k0 + kc_len; ++k) {
        float xv = AT[(size_t)k*BB + lane];
        #pragma unroll
        for (int j = 0; j < 8; ++j) acc[j] += xv * W[(size_t)(g0+j)*Ktot + k];
    }
    #pragma unroll
    for (int j = 0; j < 8; ++j) P[((size_t)kc*Nn + g0 + j)*BB + lane] = acc[j];
}

// ---------------- K4: reduce partials, GRU gates, h_new, y-h half -------------
__global__ void k_gru(const float* __restrict__ Pgi, const float* __restrict__ Pgh,
                      const float* __restrict__ b_ih, const float* __restrict__ b_hh,
                      const float* __restrict__ h, float* __restrict__ hid_out,
                      __bf16* __restrict__ y) {
    int i = blockIdx.x*256 + threadIdx.x;   // 32768 = 64b x 512h
    int b = i & 63, hh = i >> 6;
    float gi[3], gh[3];
    #pragma unroll
    for (int g3 = 0; g3 < 3; ++g3) {
        int g = g3*512 + hh;
        float s = b_ih[g];
        #pragma unroll
        for (int c = 0; c < 8; ++c) s += Pgi[((size_t)c*KK + g)*BB + b];
        gi[g3] = s;
        float s2 = b_hh[g];
        #pragma unroll
        for (int c = 0; c < 4; ++c) s2 += Pgh[((size_t)c*KK + g)*BB + b];
        gh[g3] = s2;
    }
    float r = 1.f/(1.f + expf(-(gi[0]+gh[0])));
    float z = 1.f/(1.f + expf(-(gi[1]+gh[1])));
    float n = tanhf(gi[2] + r*gh[2]);
    float h0 = h[(size_t)b*HH + hh];
    float hn = (1.f - z)*n + z*h0;
    hid_out[(size_t)b*HH + hh] = hn;
    y[(size_t)b*KK + hh] = (__bf16)hn;
}

// ---------------- K6: logits = y @ out_w + out_b  (bf16 MFMA, NN layout) ------
#define BN 128
#define BSTRIDE 40   // bf16 elems per LDS row (32 + pad, 80B, 16B-aligned rows)

__global__ __launch_bounds__(256) void k_logits(const __bf16* __restrict__ y,
        const float* __restrict__ Wv, const float* __restrict__ bias,
        float* __restrict__ C) {
    __shared__ __align__(16) __bf16 Bs[BN][BSTRIDE];
    int t = threadIdx.x;
    int n0 = blockIdx.x * BN;
    int lane = t & 63, wv = t >> 6;
    int fm = lane & 15;             // m (A) / n (B) within 16-tile
    int fk = (lane >> 4) * 8;       // k offset within 32-chunk
    int nl = t & 127, kh = t >> 7;  // staging role: column nl, k-half kh
    int gn = n0 + nl; if (gn > VV-1) gn = VV-1;
    const float* wcol = Wv + (size_t)(kh*16)*VV + gn;
    f32x4 acc[4][2];
    #pragma unroll
    for (int m = 0; m < 4; ++m)
        #pragma unroll
        for (int s = 0; s < 2; ++s)
            #pragma unroll
            for (int r = 0; r < 4; ++r) acc[m][s][r] = 0.f;

    for (int k0 = 0; k0 < KK; k0 += 32) {
        // stage B tile [32k x 128n] fp32 -> bf16 LDS [n][k] (V odd -> dword loads)
        float v[16];
        #pragma unroll
        for (int kk = 0; kk < 16; ++kk) v[kk] = wcol[(size_t)(k0+kk)*VV];
        bf16x8 w0, w1;
        #pragma unroll
        for (int kk = 0; kk < 8; ++kk) { w0[kk] = (__bf16)v[kk]; w1[kk] = (__bf16)v[kk+8]; }
        *reinterpret_cast<bf16x8*>(&Bs[nl][kh*16])     = w0;
        *reinterpret_cast<bf16x8*>(&Bs[nl][kh*16 + 8]) = w1;
        __syncthreads();
        bf16x8 bf[2], af[4];
        #pragma unroll
        for (int s = 0; s < 2; ++s)
            bf[s] = *reinterpret_cast<const bf16x8*>(&Bs[wv*32 + s*16 + fm][fk]);
        #pragma unroll
        for (int m = 0; m < 4; ++m)
            af[m] = *reinterpret_cast<const bf16x8*>(y + (size_t)(m*16 + fm)*KK + k0 + fk);
        #pragma unroll
        for (int m = 0; m < 4; ++m)
            #pragma unroll
            for (int s = 0; s < 2; ++s)
                acc[m][s] = __builtin_amdgcn_mfma_f32_16x16x32_bf16(af[m], bf[s], acc[m][s], 0, 0, 0);
        __syncthreads();
    }
    // epilogue: C layout col=lane&15, row=(lane>>4)*4+reg  [m89-verified]
    int r0 = (lane >> 4) * 4;
    #pragma unroll
    for (int s = 0; s < 2; ++s) {
        int nn = n0 + wv*32 + s*16 + fm;
        if (nn < VV) {
            float bb = bias[nn];
            #pragma unroll
            for (int m = 0; m < 4; ++m)
                #pragma unroll
                for (int r = 0; r < 4; ++r)
                    C[(size_t)(m*16 + r0 + r)*VV + nn] = acc[m][s][r] + bb;
        }
    }
}

// ---------------- K7: per-row logsumexp -------------------------------------
__global__ void k_lse(const float* __restrict__ logits, float* __restrict__ lse) {
    __shared__ float red[8];
    int b = blockIdx.x, t = threadIdx.x;
    const float* row = logits + (size_t)b*VV;
    float m = -3.0e38f;
    for (int v = t; v < VV; v += 256) m = fmaxf(m, row[v]);
    #pragma unroll
    for (int off = 32; off; off >>= 1) m = fmaxf(m, __shfl_xor(m, off));
    if ((t & 63) == 0) red[t >> 6] = m;
    __syncthreads();
    m = fmaxf(fmaxf(red[0], red[1]), fmaxf(red[2], red[3]));
    float s = 0.f;
    for (int v = t; v < VV; v += 256) s += __expf(row[v] - m);
    #pragma unroll
    for (int off = 32; off; off >>= 1) s += __shfl_xor(s, off);
    if ((t & 63) == 0) red[4 + (t >> 6)] = s;
    __syncthreads();
    if (t == 0) lse[b] = m + logf(red[4] + red[5] + red[6] + red[7]);
}

// ---------------- K8: logp = logits - lse (in place) ------------------------
__global__ void k_logp(float* __restrict__ logits, const float* __restrict__ lse) {
    int b = blockIdx.y;
    int v0 = blockIdx.x*1024 + threadIdx.x;
    float c = lse[b];
    float* row = logits + (size_t)b*VV;
    #pragma unroll
    for (int j = 0; j < 4; ++j) {
        int vv = v0 + j*256;
        if (vv < VV) row[vv] -= c;
    }
}

extern "C" void kernel_launch(void* const* d_in, const int* in_sizes, int n_in,
                              void* d_out, int out_size, void* d_ws, size_t ws_size,
                              hipStream_t stream) {
    const int*   x     = (const int*)d_in[0];
    const float* h     = (const float*)d_in[1];
    const float* enc   = (const float*)d_in[2];
    // d_in[3] = use_cuda (dead), d_in[5]/d_in[6] = attn_w/attn_b (dead: softmax over singleton -> uniform)
    const float* emb   = (const float*)d_in[4];
    const float* w_ih  = (const float*)d_in[7];
    const float* w_hh  = (const float*)d_in[8];
    const float* b_ih  = (const float*)d_in[9];
    const float* b_hh  = (const float*)d_in[10];
    const float* out_w = (const float*)d_in[11];
    const float* out_b = (const float*)d_in[12];
    float* out = (float*)d_out;
    char*  ws  = (char*)d_ws;

    float*  actT = (float*)ws;                      // [2048][64] f32: xe|ctx|h0T  (512KB)
    __bf16* y    = (__bf16*)(ws + 524288);          // [64][1536] bf16             (192KB)
    float*  lse  = (float*)(ws + 720896);           // [64]
    float*  ctxp = (float*)(ws + (1u<<20));         // [64][16][1024] f32          (4MB)
    float*  Pgi  = ctxp;                            // reuse after k_prep          (3MB)
    float*  Pgh  = (float*)(ws + 4u*(1u<<20));      // [4][1536][64]               (1.5MB)

    const size_t OFF_H = (size_t)BB*VV;             // hidden output offset
    const size_t OFF_A = OFF_H + (size_t)BB*HH;     // attn_weights output offset

    k_ctx_partial<<<dim3(64,16), 256, 0, stream>>>(enc, ctxp);
    k_prep<<<64, 256, 0, stream>>>(ctxp, x, emb, h, actT, y, out + OFF_A);
    k_small_gemm<<<dim3(192,8), 64, 0, stream>>>(actT, w_ih, Pgi, 1536, 192, 1536);
    k_small_gemm<<<dim3(192,4), 64, 0, stream>>>(actT + (size_t)1536*BB, w_hh, Pgh, 512, 128, 1536);
    k_gru<<<128, 256, 0, stream>>>(Pgi, Pgh, b_ih, b_hh, h, out + OFF_H, y);
    k_logits<<<393, 256, 0, stream>>>(y, out_w, out_b, out);
    k_lse<<<64, 256, 0, stream>>>(out, lse);
    k_logp<<<dim3(50,64), 256, 0, stream>>>(out, lse);
}